// Round 1
// 615.357 us; speedup vs baseline: 1.0091x; 1.0091x over previous
//
#include <hip/hip_runtime.h>

typedef unsigned short ushort_t;
typedef unsigned int   u32;
typedef __attribute__((ext_vector_type(8))) short bf16x8;
typedef __attribute__((ext_vector_type(4))) float f32x4;

#define NNODES 100000
#define DIM    256
#define NEDGE  300000
#define KTOT   512          // virtual K = [agg | xin]
#define KSTEPS 16           // BK = 32
#define BROWS  128          // rows per block (4 row-groups x 32 rows)
#define NTILES 16           // 256 / 16 column tiles (total)
#define WCT    8            // col-tiles per wave: N split across 2 waves
#define SLICE  16384        // ushorts per 32-k slice: 2 planes x 256 n x 32 k
// slice layout (ushort units): plane*8192 + ct*512 + quad*128 + nn*8 + j
//   => chunk c = plane*1024 + ct*64 + (quad*16 + nn); 16B chunks, lane-linear

// ================= CSR build (counting sort by dst) =================

__global__ void count_kernel(const int* __restrict__ dst, int* __restrict__ cnt, int E) {
    int e = blockIdx.x * blockDim.x + threadIdx.x;
    if (e < E) atomicAdd(&cnt[dst[e]], 1);
}

__global__ void scan1(const int* __restrict__ cnt, int* __restrict__ partial, int n) {
    __shared__ int s[256];
    int i = blockIdx.x * 256 + threadIdx.x;
    s[threadIdx.x] = (i < n) ? cnt[i] : 0;
    __syncthreads();
    for (int off = 128; off > 0; off >>= 1) {
        if (threadIdx.x < off) s[threadIdx.x] += s[threadIdx.x + off];
        __syncthreads();
    }
    if (threadIdx.x == 0) partial[blockIdx.x] = s[0];
}

__global__ void scan2(int* __restrict__ partial, int nb) {
    __shared__ int s[512];
    int t = threadIdx.x;
    int orig = (t < nb) ? partial[t] : 0;
    s[t] = orig;
    __syncthreads();
    for (int off = 1; off < 512; off <<= 1) {
        int v = (t >= off) ? s[t - off] : 0;
        __syncthreads();
        s[t] += v;
        __syncthreads();
    }
    if (t < nb) partial[t] = s[t] - orig;  // exclusive
}

__global__ void scan3(const int* __restrict__ cnt, const int* __restrict__ partial,
                      int* __restrict__ row_start, int n) {
    __shared__ int s[256];
    int i = blockIdx.x * 256 + threadIdx.x;
    int v = (i < n) ? cnt[i] : 0;
    s[threadIdx.x] = v;
    __syncthreads();
    for (int off = 1; off < 256; off <<= 1) {
        int t = (threadIdx.x >= off) ? s[threadIdx.x - off] : 0;
        __syncthreads();
        s[threadIdx.x] += t;
        __syncthreads();
    }
    if (i < n) row_start[i] = partial[blockIdx.x] + s[threadIdx.x] - v;
}

__global__ void fill_csr(const int* __restrict__ src, const int* __restrict__ dst,
                         const int* __restrict__ row_start, int* __restrict__ cursor,
                         int* __restrict__ esrc, int E) {
    int e = blockIdx.x * blockDim.x + threadIdx.x;
    if (e < E) {
        int d = dst[e];
        int pos = row_start[d] + atomicAdd(&cursor[d], 1);
        esrc[pos] = src[e];
    }
}

// ================= aggregation: one wave per node =================
__global__ __launch_bounds__(256) void aggregate(
    const int* __restrict__ esrc, const int* __restrict__ row_start,
    const int* __restrict__ cnt, const float* __restrict__ x, float* __restrict__ agg)
{
    int node = (blockIdx.x * blockDim.x + threadIdx.x) >> 6;
    int lane = threadIdx.x & 63;
    if (node >= NNODES) return;
    int start = row_start[node];
    int c = cnt[node];
    float4 acc = make_float4(0.f, 0.f, 0.f, 0.f);
    for (int i = 0; i < c; i++) {
        int s = esrc[start + i];
        float4 v = ((const float4*)(x + (size_t)s * DIM))[lane];
        acc.x += v.x; acc.y += v.y; acc.z += v.z; acc.w += v.w;
    }
    float inv = (c > 0) ? 1.0f / (float)c : 0.0f;
    ((float4*)(agg + (size_t)node * DIM))[lane] =
        make_float4(acc.x * inv, acc.y * inv, acc.z * inv, acc.w * inv);
}

// ========== weight split + swizzle into MFMA-fragment/LDS-linear order ==========
__global__ void conv_weights(const float* __restrict__ Wl, const float* __restrict__ Wr,
                             ushort_t* __restrict__ Bsw) {
    int idx = blockIdx.x * 256 + threadIdx.x;      // n*512 + k
    if (idx >= 256 * KTOT) return;
    int n = idx >> 9, k = idx & 511;
    float v = (k < DIM) ? Wl[n * DIM + k] : Wr[n * DIM + (k - DIM)];
    unsigned u = __float_as_uint(v);
    unsigned hb = u & 0xFFFF0000u;
    float lo = v - __uint_as_float(hb);
    int ks = k >> 5, q = (k >> 3) & 3, j = k & 7;
    int ct = n >> 4, nn = n & 15;
    int base = ks * SLICE + ct * 512 + q * 128 + nn * 8 + j;
    Bsw[base]        = (ushort_t)(u >> 16);                      // hi plane
    Bsw[base + 8192] = (ushort_t)(__float_as_uint(lo) >> 16);    // lo plane
}

// ================= helpers =================

// Async direct global->LDS staging of one 32 KB slice by a 512-thread block.
// LDS dest is wave-uniform base + lane*16 (HW rule); layout is lane-linear so
// chunk c = wave*64 + lane + i*512 lands exactly at buf + c*16B.
__device__ __forceinline__ void stage_b_async(const ushort_t* __restrict__ slice,
                                              ushort_t* buf, int tid) {
    const int wave = tid >> 6;
    #pragma unroll
    for (int i = 0; i < 4; i++) {
        const int c  = tid + i * 512;            // per-lane 16B chunk index
        const int cb = wave * 64 + i * 512;      // wave-uniform base chunk
        __builtin_amdgcn_global_load_lds(
            (const __attribute__((address_space(1))) u32*)(slice + (size_t)c * 8),
            (__attribute__((address_space(3))) u32*)(buf + cb * 8),
            16, 0, 0);
    }
}

__device__ __forceinline__ void load_a(const float* __restrict__ base, int row0, int row1,
                                       int kk, int M, float* va /*16 floats*/) {
    if (row0 < M) {
        *(float4*)(va + 0) = *(const float4*)(base + (size_t)row0 * DIM + kk);
        *(float4*)(va + 4) = *(const float4*)(base + (size_t)row0 * DIM + kk + 4);
    } else {
        *(float4*)(va + 0) = make_float4(0.f, 0.f, 0.f, 0.f);
        *(float4*)(va + 4) = make_float4(0.f, 0.f, 0.f, 0.f);
    }
    if (row1 < M) {
        *(float4*)(va + 8)  = *(const float4*)(base + (size_t)row1 * DIM + kk);
        *(float4*)(va + 12) = *(const float4*)(base + (size_t)row1 * DIM + kk + 4);
    } else {
        *(float4*)(va + 8)  = make_float4(0.f, 0.f, 0.f, 0.f);
        *(float4*)(va + 12) = make_float4(0.f, 0.f, 0.f, 0.f);
    }
}

__device__ __forceinline__ void split8(const float* __restrict__ a, bf16x8& h, bf16x8& l) {
    #pragma unroll
    for (int i = 0; i < 8; i++) {
        float x = a[i];
        unsigned u = __float_as_uint(x);
        unsigned hb = u & 0xFFFF0000u;
        h[i] = (short)(u >> 16);
        float lo = x - __uint_as_float(hb);
        l[i] = (short)(__float_as_uint(lo) >> 16);
    }
}

// ================= MFMA GEMM: out = [agg|xin] @ B^T + bias (split-bf16, fp32 acc) ===============
// 512 threads / 8 waves per block. Wave w: row-group w>>1 (32 rows), col-group w&1 (8 col-tiles).
// acc = 2x8 f32x4 = 64 regs/wave -> total <=128 -> 4 waves/SIMD (16 waves/CU with 2 blocks/CU).
__global__ __launch_bounds__(512, 4) void sage_gemm_mfma(
    const float* __restrict__ agg, const float* __restrict__ xin,
    const ushort_t* __restrict__ Bsw,
    const float* __restrict__ bias, float* __restrict__ out, int M, int do_relu)
{
    __shared__ __align__(16) ushort_t Bs[2][SLICE];

    const int tid  = threadIdx.x;
    const int lane = tid & 63;
    const int wave = tid >> 6;          // 0..7
    const int lrow = lane & 15;
    const int quad = lane >> 4;
    const int rg   = wave >> 1;         // row-group 0..3
    const int cg   = wave & 1;          // col-group 0..1

    const int rowbase = blockIdx.x * BROWS + rg * 32;
    const int arow0 = rowbase + lrow;
    const int arow1 = rowbase + 16 + lrow;
    const int kq    = quad * 8;
    const int ctbase = cg * WCT;        // 0 or 8

    f32x4 acc[2][WCT];
    #pragma unroll
    for (int i = 0; i < 2; i++)
        #pragma unroll
        for (int j = 0; j < WCT; j++)
            acc[i][j] = (f32x4){0.f, 0.f, 0.f, 0.f};

    float aN[16];
    stage_b_async(Bsw, &Bs[0][0], tid);
    load_a(agg, arow0, arow1, kq, M, aN);

    for (int ks = 0; ks < KSTEPS; ks++) {
        __syncthreads();                 // drains vmcnt: buf[ks&1] + aN both ready
        if (ks + 1 < KSTEPS)
            stage_b_async(Bsw + (size_t)(ks + 1) * SLICE, &Bs[(ks + 1) & 1][0], tid);

        bf16x8 ah0, al0, ah1, al1;
        split8(aN + 0, ah0, al0);
        split8(aN + 8, ah1, al1);

        if (ks + 1 < KSTEPS) {           // reissue prefetch into aN (regs reused after split)
            int ks1 = ks + 1;
            const float* base = (ks1 < 8) ? agg : xin;
            int kk = ((ks1 < 8) ? ks1 * 32 : (ks1 - 8) * 32) + kq;
            load_a(base, arow0, arow1, kk, M, aN);
        }

        const ushort_t* bp = &Bs[ks & 1][ctbase * 512 + lane * 8];
        #pragma unroll
        for (int j = 0; j < WCT; j++) {
            const bf16x8 bh = *(const bf16x8*)(bp + j * 512);
            const bf16x8 bl = *(const bf16x8*)(bp + 8192 + j * 512);
            acc[0][j] = __builtin_amdgcn_mfma_f32_16x16x32_bf16(ah0, bh, acc[0][j], 0, 0, 0);
            acc[1][j] = __builtin_amdgcn_mfma_f32_16x16x32_bf16(ah1, bh, acc[1][j], 0, 0, 0);
            acc[0][j] = __builtin_amdgcn_mfma_f32_16x16x32_bf16(al0, bh, acc[0][j], 0, 0, 0);
            acc[1][j] = __builtin_amdgcn_mfma_f32_16x16x32_bf16(al1, bh, acc[1][j], 0, 0, 0);
            acc[0][j] = __builtin_amdgcn_mfma_f32_16x16x32_bf16(ah0, bl, acc[0][j], 0, 0, 0);
            acc[1][j] = __builtin_amdgcn_mfma_f32_16x16x32_bf16(ah1, bl, acc[1][j], 0, 0, 0);
        }
    }

    // ---- epilogue: bias + optional relu; C layout: col=lane&15, row=quad*4+reg ----
    #pragma unroll
    for (int j = 0; j < WCT; j++) {
        const int col = (ctbase + j) * 16 + lrow;
        const float bv = bias[col];
        #pragma unroll
        for (int rt = 0; rt < 2; rt++) {
            const int row = rowbase + rt * 16 + quad * 4;
            #pragma unroll
            for (int r = 0; r < 4; r++) {
                if (row + r < M) {
                    float v = acc[rt][j][r] + bv;
                    if (do_relu) v = fmaxf(v, 0.f);
                    out[(size_t)(row + r) * DIM + col] = v;
                }
            }
        }
    }
}

extern "C" void kernel_launch(void* const* d_in, const int* in_sizes, int n_in,
                              void* d_out, int out_size, void* d_ws, size_t ws_size,
                              hipStream_t stream) {
    const int*   edge = (const int*)d_in[0];
    const int*   src  = edge;
    const int*   dst  = edge + NEDGE;
    const float* x    = (const float*)d_in[1];
    const float* Wl1  = (const float*)d_in[2];
    const float* Wr1  = (const float*)d_in[3];
    const float* b1   = (const float*)d_in[4];
    const float* Wl2  = (const float*)d_in[5];
    const float* Wr2  = (const float*)d_in[6];
    const float* b2   = (const float*)d_in[7];
    const float* Wl3  = (const float*)d_in[8];
    const float* Wr3  = (const float*)d_in[9];
    const float* b3   = (const float*)d_in[10];

    const size_t feat = (size_t)NNODES * DIM;
    float*    agg       = (float*)d_ws;
    float*    h2        = agg + feat;
    int*      cnt       = (int*)(h2 + feat);
    int*      row_start = cnt + NNODES;
    int*      cursor    = row_start + NNODES;
    int*      partial   = cursor + NNODES;            // 512
    int*      esrc      = partial + 512;              // NEDGE
    ushort_t* Bsw       = (ushort_t*)(esrc + NEDGE);  // KSTEPS*SLICE ushorts (512 KB)
    float*    h1        = (float*)d_out;   // layer-1 out in d_out; rewritten by layer 3

    const int nScanBlocks = (NNODES + 255) / 256;

    // ---- CSR build (edge structure shared by all 3 layers) ----
    hipMemsetAsync(cnt, 0, NNODES * sizeof(int), stream);
    hipMemsetAsync(cursor, 0, NNODES * sizeof(int), stream);
    count_kernel<<<(NEDGE + 255) / 256, 256, 0, stream>>>(dst, cnt, NEDGE);
    scan1<<<nScanBlocks, 256, 0, stream>>>(cnt, partial, NNODES);
    scan2<<<1, 512, 0, stream>>>(partial, nScanBlocks);
    scan3<<<nScanBlocks, 256, 0, stream>>>(cnt, partial, row_start, NNODES);
    fill_csr<<<(NEDGE + 255) / 256, 256, 0, stream>>>(src, dst, row_start, cursor, esrc, NEDGE);

    const int aggBlocks  = (NNODES * 64 + 255) / 256;
    const int gemmBlocks = (NNODES + BROWS - 1) / BROWS;
    const int convBlocks = (256 * KTOT + 255) / 256;

    // ---- layer 1 ----
    conv_weights<<<convBlocks, 256, 0, stream>>>(Wl1, Wr1, Bsw);
    aggregate<<<aggBlocks, 256, 0, stream>>>(esrc, row_start, cnt, x, agg);
    sage_gemm_mfma<<<gemmBlocks, 512, 0, stream>>>(agg, x, Bsw, b1, h1, NNODES, 1);

    // ---- layer 2 ----
    conv_weights<<<convBlocks, 256, 0, stream>>>(Wl2, Wr2, Bsw);
    aggregate<<<aggBlocks, 256, 0, stream>>>(esrc, row_start, cnt, h1, agg);
    sage_gemm_mfma<<<gemmBlocks, 512, 0, stream>>>(agg, h1, Bsw, b2, h2, NNODES, 1);

    // ---- layer 3 ----
    conv_weights<<<convBlocks, 256, 0, stream>>>(Wl3, Wr3, Bsw);
    aggregate<<<aggBlocks, 256, 0, stream>>>(esrc, row_start, cnt, h2, agg);
    sage_gemm_mfma<<<gemmBlocks, 512, 0, stream>>>(agg, h2, Bsw, b3, (float*)d_out, NNODES, 0);
}